// Round 6
// baseline (2349.932 us; speedup 1.0000x reference)
//
#include <hip/hip_runtime.h>

#define BB    8
#define LL    2
#define DIM   1024
#define NH    8
#define HD    128
#define BS    16
#define NB    129
#define NSPLIT 32
#define NBLK  768
#define SCALE 0.08838834764831845f   // 1/sqrt(128)
#define EPS   1e-5f

// ---- software grid barrier: monotonic counter, device-scope, bounded spin ----
__device__ __forceinline__ void gsync(unsigned* cnt, unsigned target) {
  __syncthreads();                       // rendezvous; each wave drains stores to L2
  if (threadIdx.x == 0) {
    __threadfence();                     // agent fence: writeback to device coherence point
    __hip_atomic_fetch_add(cnt, 1u, __ATOMIC_RELEASE, __HIP_MEMORY_SCOPE_AGENT);
    unsigned v = __hip_atomic_load(cnt, __ATOMIC_ACQUIRE, __HIP_MEMORY_SCOPE_AGENT);
    long iters = 0;
    while (v < target && iters < 20000000L) {
      __builtin_amdgcn_s_sleep(1);
      v = __hip_atomic_load(cnt, __ATOMIC_ACQUIRE, __HIP_MEMORY_SCOPE_AGENT);
      ++iters;
    }
    __threadfence();                     // invalidate stale lines before block proceeds
  }
  __syncthreads();
}

// ---- per-batch rms scales from 8 register rows -> scale[8] ----
__device__ __forceinline__ void rms_scales8(const float4 xr[8], float* lds, float* scale) {
  int tid = threadIdx.x;
#pragma unroll
  for (int b = 0; b < 8; ++b)
    lds[tid * 9 + b] = xr[b].x * xr[b].x + xr[b].y * xr[b].y +
                       xr[b].z * xr[b].z + xr[b].w * xr[b].w;
  __syncthreads();
  int bb = tid >> 5, i = tid & 31;
  float s = 0.0f;
#pragma unroll
  for (int j = 0; j < 8; ++j) s += lds[(i + 32 * j) * 9 + bb];
#pragma unroll
  for (int o = 16; o; o >>= 1) s += __shfl_xor(s, o);
  if (i == 0) scale[bb] = rsqrtf(s * (1.0f / DIM) + EPS);
  __syncthreads();
}

// ---- LDS-transpose reduce of 8 accumulators; lds reusable after return ----
__device__ __forceinline__ float block_reduce8(const float acc[8], float* lds, int* bb_out) {
  int tid = threadIdx.x;
#pragma unroll
  for (int b = 0; b < 8; ++b) lds[tid * 9 + b] = acc[b];
  __syncthreads();
  int bb = tid >> 5, i = tid & 31;
  float s = 0.0f;
#pragma unroll
  for (int j = 0; j < 8; ++j) s += lds[(i + 32 * j) * 9 + bb];
#pragma unroll
  for (int o = 16; o; o >>= 1) s += __shfl_xor(s, o);
  __syncthreads();
  *bb_out = bb;
  return s;
}

__global__ void __launch_bounds__(256, 3) mega_k(
    const float* __restrict__ x0, const float* __restrict__ kheap,
    const float* __restrict__ vheap, const int* __restrict__ bt,
    const int* __restrict__ ctxp, const float* __restrict__ wq,
    const float* __restrict__ wk, const float* __restrict__ wv,
    const float* __restrict__ wo, const float* __restrict__ w1,
    const float* __restrict__ w2, const float* __restrict__ w3,
    const float* __restrict__ norm1, const float* __restrict__ norm2,
    const float* __restrict__ normf, float* __restrict__ out,
    float* __restrict__ wsb) {
  __shared__ float lds[256 * 9];      // 9216 B
  __shared__ float scale[8];
  unsigned* cnt = (unsigned*)wsb;     // barrier counter (memset to 0 each launch)
  float* q    = wsb + 64;
  float* k    = wsb + 64 + 8192;
  float* v    = wsb + 64 + 16384;
  float* g    = wsb + 64 + 24576;
  float* xa   = wsb + 64 + 57344;
  float* xf   = wsb + 64 + 65536;
  float* ab   = wsb + 64 + 73728;
  float* pm   = wsb + 64 + 81920;
  float* ps   = wsb + 64 + 98304;
  float* pacc = wsb + 64 + 114688;
  const size_t WD = (size_t)DIM * DIM;
  const size_t WF = (size_t)4 * DIM * DIM;
  int bid = blockIdx.x, tid = threadIdx.x;
  unsigned bar = 0;

  for (int l = 0; l < LL; ++l) {
    const float* xin = (l == 0) ? x0 : xf;

    // ================= QKV GEMV + fused RMSNorm (3072 rows) =================
    {
      float4 xr[8];
#pragma unroll
      for (int bb = 0; bb < 8; ++bb)
        xr[bb] = *(const float4*)(xin + bb * DIM + tid * 4);
      rms_scales8(xr, lds, scale);
      float4 wn = *(const float4*)(norm1 + l * DIM + tid * 4);
#pragma unroll
      for (int bb = 0; bb < 8; ++bb) {
        xr[bb].x *= wn.x; xr[bb].y *= wn.y; xr[bb].z *= wn.z; xr[bb].w *= wn.w;
      }
      for (int row = bid; row < 3 * DIM; row += NBLK) {
        int mat = row >> 10, r = row & 1023;
        const float* W = (mat == 0 ? wq : mat == 1 ? wk : wv) + l * WD + (size_t)r * DIM;
        float4 w4 = *(const float4*)(W + tid * 4);
        float acc[8];
#pragma unroll
        for (int bb = 0; bb < 8; ++bb)
          acc[bb] = w4.x * xr[bb].x + w4.y * xr[bb].y + w4.z * xr[bb].z + w4.w * xr[bb].w;
        int bb; float s = block_reduce8(acc, lds, &bb);
        if ((tid & 31) == 0) {
          float* dst = (mat == 0 ? q : mat == 1 ? k : v);
          dst[bb * DIM + r] = s * scale[bb];
        }
      }
    }
    gsync(cnt, NBLK * (++bar));

    // ================= attention partials (NSPLIT x 64 units) =================
    {
      int grp = tid >> 5, lane = tid & 31;
      for (int u = bid; u < NSPLIT * 64; u += NBLK) {
        int c = u >> 6, bh = u & 63;
        int b = bh >> 3, hh = bh & 7;
        int ctx = ctxp[b];
        int CH = (ctx + NSPLIT - 1) / NSPLIT;
        int t0 = c * CH;
        int t1 = t0 + CH; if (t1 > ctx) t1 = ctx;
        int last = ctx - 1;
        const float4 q4 = *(const float4*)(q + b * DIM + hh * HD + lane * 4);
        const int* btb = bt + (size_t)l * BB * NB + b * NB;
        float m = -1e30f, ssum = 0.0f;
        float4 acc = make_float4(0.f, 0.f, 0.f, 0.f);
        for (int t = t0 + grp; t < t1; t += 8) {
          const float *Kp, *Vp;
          if (t == last) {
            Kp = k + b * DIM + hh * HD;
            Vp = v + b * DIM + hh * HD;
          } else {
            int pb = btb[t >> 4];
            size_t base = ((((size_t)pb * BS) + (t & 15)) * NH + hh) * HD;
            Kp = kheap + base;
            Vp = vheap + base;
          }
          float4 k4 = *(const float4*)(Kp + lane * 4);
          float4 v4 = *(const float4*)(Vp + lane * 4);
          float sc = q4.x * k4.x + q4.y * k4.y + q4.z * k4.z + q4.w * k4.w;
#pragma unroll
          for (int o = 16; o; o >>= 1) sc += __shfl_xor(sc, o);
          sc *= SCALE;
          float mnew = fmaxf(m, sc);
          float f = __expf(m - mnew);
          float p = __expf(sc - mnew);
          ssum = ssum * f + p;
          acc.x = acc.x * f + p * v4.x;
          acc.y = acc.y * f + p * v4.y;
          acc.z = acc.z * f + p * v4.z;
          acc.w = acc.w * f + p * v4.w;
          m = mnew;
        }
        int pi = bh * 256 + c * 8 + grp;
        if (lane == 0) { pm[pi] = m; ps[pi] = ssum; }
        *(float4*)(pacc + (size_t)pi * HD + lane * 4) = acc;
      }
    }
    gsync(cnt, NBLK * (++bar));

    // ================= attention reduce (64 units, 256 partials each) =================
    if (bid < 64) {
      int bh = bid;
      float* red = lds;           // 256 floats
      float* fb  = lds + 256;     // 256 floats
      float mi = pm[bh * 256 + tid];
      red[tid] = mi; __syncthreads();
#pragma unroll
      for (int o = 128; o; o >>= 1) {
        if (tid < o) red[tid] = fmaxf(red[tid], red[tid + o]);
        __syncthreads();
      }
      float M = red[0]; __syncthreads();
      float fi = __expf(mi - M);
      fb[tid] = fi;
      red[tid] = ps[bh * 256 + tid] * fi;
      __syncthreads();
#pragma unroll
      for (int o = 128; o; o >>= 1) {
        if (tid < o) red[tid] += red[tid + o];
        __syncthreads();
      }
      float inv = 1.0f / red[0];
      int d = tid & 127, hp = tid >> 7;
      float od = 0.0f;
      const float* pb = pacc + ((size_t)bh * 256 + hp * 128) * HD + d;
      for (int p = 0; p < 128; ++p) od += pb[(size_t)p * HD] * fb[hp * 128 + p];
      __syncthreads();
      red[tid] = od; __syncthreads();
      if (tid < 128) ab[bh * HD + tid] = (red[tid] + red[tid + 128]) * inv;
    }
    gsync(cnt, NBLK * (++bar));

    // ================= o-proj + residual (1024 rows) =================
    for (int r = bid; r < DIM; r += NBLK) {
      float4 w4 = *(const float4*)(wo + l * WD + (size_t)r * DIM + tid * 4);
      float acc[8];
#pragma unroll
      for (int bb = 0; bb < 8; ++bb) {
        float4 h4 = *(const float4*)(ab + bb * DIM + tid * 4);
        acc[bb] = w4.x * h4.x + w4.y * h4.y + w4.z * h4.z + w4.w * h4.w;
      }
      int bb; float s = block_reduce8(acc, lds, &bb);
      if ((tid & 31) == 0) xa[bb * DIM + r] = s + xin[bb * DIM + r];
    }
    gsync(cnt, NBLK * (++bar));

    // ================= FFN w1/w3 + SwiGLU + fused RMSNorm (4096 rows) =================
    {
      float4 xr[8];
#pragma unroll
      for (int bb = 0; bb < 8; ++bb)
        xr[bb] = *(const float4*)(xa + bb * DIM + tid * 4);
      rms_scales8(xr, lds, scale);
      float4 wn = *(const float4*)(norm2 + l * DIM + tid * 4);
#pragma unroll
      for (int bb = 0; bb < 8; ++bb) {
        xr[bb].x *= wn.x; xr[bb].y *= wn.y; xr[bb].z *= wn.z; xr[bb].w *= wn.w;
      }
      for (int r = bid; r < 4 * DIM; r += NBLK) {
        float4 w14 = *(const float4*)(w1 + l * WF + (size_t)r * DIM + tid * 4);
        float4 w34 = *(const float4*)(w3 + l * WF + (size_t)r * DIM + tid * 4);
        float a[8], c[8];
#pragma unroll
        for (int bb = 0; bb < 8; ++bb) {
          a[bb] = w14.x * xr[bb].x + w14.y * xr[bb].y + w14.z * xr[bb].z + w14.w * xr[bb].w;
          c[bb] = w34.x * xr[bb].x + w34.y * xr[bb].y + w34.z * xr[bb].z + w34.w * xr[bb].w;
        }
        int bb;
        float sa = block_reduce8(a, lds, &bb);
        float sc = block_reduce8(c, lds, &bb);
        if ((tid & 31) == 0) {
          float sv = sa * scale[bb];
          sv = sv / (1.0f + __expf(-sv));      // silu
          g[bb * 4 * DIM + r] = sv * (sc * scale[bb]);
        }
      }
    }
    gsync(cnt, NBLK * (++bar));

    // ================= FFN w2 + residual (1024 rows, K=4096) =================
    for (int r = bid; r < DIM; r += NBLK) {
      const float* W = w2 + l * WF + (size_t)r * 4 * DIM;
      float acc[8] = {};
#pragma unroll
      for (int j4 = 0; j4 < 4; ++j4) {
        int j = j4 * 1024 + tid * 4;
        float4 w4 = *(const float4*)(W + j);
#pragma unroll
        for (int bb = 0; bb < 8; ++bb) {
          float4 g4 = *(const float4*)(g + bb * 4 * DIM + j);
          acc[bb] += w4.x * g4.x + w4.y * g4.y + w4.z * g4.z + w4.w * g4.w;
        }
      }
      int bb; float s = block_reduce8(acc, lds, &bb);
      if ((tid & 31) == 0) xf[bb * DIM + r] = s + xa[bb * DIM + r];
    }
    gsync(cnt, NBLK * (++bar));
  }

  // ================= final RMSNorm (8 rows) =================
  if (bid < BB) {
    int b = bid;
    float4 vv = ((const float4*)(xf + (size_t)b * DIM))[tid];
    float s = vv.x * vv.x + vv.y * vv.y + vv.z * vv.z + vv.w * vv.w;
#pragma unroll
    for (int o = 32; o; o >>= 1) s += __shfl_xor(s, o);
    if ((tid & 63) == 0) lds[tid >> 6] = s;
    __syncthreads();
    float tot = lds[0] + lds[1] + lds[2] + lds[3];
    float r = rsqrtf(tot * (1.0f / DIM) + EPS);
    float4 wv4 = ((const float4*)normf)[tid];
    float4 o4;
    o4.x = vv.x * r * wv4.x; o4.y = vv.y * r * wv4.y;
    o4.z = vv.z * r * wv4.z; o4.w = vv.w * r * wv4.w;
    ((float4*)(out + (size_t)b * DIM))[tid] = o4;
  }
}

extern "C" void kernel_launch(void* const* d_in, const int* in_sizes, int n_in,
                              void* d_out, int out_size, void* d_ws, size_t ws_size,
                              hipStream_t stream) {
  const float* x0    = (const float*)d_in[0];
  const float* kheap = (const float*)d_in[1];
  const float* vheap = (const float*)d_in[2];
  const int*   bt    = (const int*)d_in[3];
  // d_in[4] = slot_mapping (int64) — unused; derived from context_lens instead.
  const int*   ctx   = (const int*)d_in[5];
  const float* wq    = (const float*)d_in[6];
  const float* wk    = (const float*)d_in[7];
  const float* wv    = (const float*)d_in[8];
  const float* wo    = (const float*)d_in[9];
  const float* w1    = (const float*)d_in[10];
  const float* w2    = (const float*)d_in[11];
  const float* w3    = (const float*)d_in[12];
  const float* norm1 = (const float*)d_in[13];
  const float* norm2 = (const float*)d_in[14];
  const float* normf = (const float*)d_in[15];

  // zero the barrier counter (graph-legal memset node, replayed each call)
  hipMemsetAsync(d_ws, 0, 256, stream);

  mega_k<<<NBLK, 256, 0, stream>>>(x0, kheap, vheap, bt, ctx, wq, wk, wv, wo,
                                   w1, w2, w3, norm1, norm2, normf,
                                   (float*)d_out, (float*)d_ws);
}

// Round 7
// 1265.731 us; speedup vs baseline: 1.8566x; 1.8566x over previous
//
#include <hip/hip_runtime.h>

#define BB    8
#define LL    2
#define DIM   1024
#define NH    8
#define HD    128
#define BS    16
#define NB    129
#define NSPLIT 32
#define NBLK  768
#define SCALE 0.08838834764831845f   // 1/sqrt(128)
#define EPS   1e-5f

// ---- software grid barrier: monotonic counter, relaxed poll, single acquire ----
__device__ __forceinline__ void gsync(unsigned* cnt, unsigned target) {
  __syncthreads();                       // block rendezvous
  if (threadIdx.x == 0) {
    __threadfence();                     // release: write back dirty L2 to coherence point
    __hip_atomic_fetch_add(cnt, 1u, __ATOMIC_RELEASE, __HIP_MEMORY_SCOPE_AGENT);
    // RELAXED polls: served at the coherence point, no per-poll cache invalidate.
    unsigned v = __hip_atomic_load(cnt, __ATOMIC_RELAXED, __HIP_MEMORY_SCOPE_AGENT);
    long iters = 0;
    while (v < target && iters < 400000L) {   // bounded: ~80 ms worst case, no hang
      __builtin_amdgcn_s_sleep(8);            // ~512 cycles backoff
      v = __hip_atomic_load(cnt, __ATOMIC_RELAXED, __HIP_MEMORY_SCOPE_AGENT);
      ++iters;
    }
    __threadfence();                     // acquire: invalidate stale lines ONCE
  }
  __syncthreads();
}

// ---- per-batch rms scales from 8 register rows -> scale[8] ----
__device__ __forceinline__ void rms_scales8(const float4 xr[8], float* lds, float* scale) {
  int tid = threadIdx.x;
#pragma unroll
  for (int b = 0; b < 8; ++b)
    lds[tid * 9 + b] = xr[b].x * xr[b].x + xr[b].y * xr[b].y +
                       xr[b].z * xr[b].z + xr[b].w * xr[b].w;
  __syncthreads();
  int bb = tid >> 5, i = tid & 31;
  float s = 0.0f;
#pragma unroll
  for (int j = 0; j < 8; ++j) s += lds[(i + 32 * j) * 9 + bb];
#pragma unroll
  for (int o = 16; o; o >>= 1) s += __shfl_xor(s, o);
  if (i == 0) scale[bb] = rsqrtf(s * (1.0f / DIM) + EPS);
  __syncthreads();
}

// ---- LDS-transpose reduce of 8 accumulators; lds reusable after return ----
__device__ __forceinline__ float block_reduce8(const float acc[8], float* lds, int* bb_out) {
  int tid = threadIdx.x;
#pragma unroll
  for (int b = 0; b < 8; ++b) lds[tid * 9 + b] = acc[b];
  __syncthreads();
  int bb = tid >> 5, i = tid & 31;
  float s = 0.0f;
#pragma unroll
  for (int j = 0; j < 8; ++j) s += lds[(i + 32 * j) * 9 + bb];
#pragma unroll
  for (int o = 16; o; o >>= 1) s += __shfl_xor(s, o);
  __syncthreads();
  *bb_out = bb;
  return s;
}

__global__ void __launch_bounds__(256, 3) mega_k(
    const float* __restrict__ x0, const float* __restrict__ kheap,
    const float* __restrict__ vheap, const int* __restrict__ bt,
    const int* __restrict__ ctxp, const float* __restrict__ wq,
    const float* __restrict__ wk, const float* __restrict__ wv,
    const float* __restrict__ wo, const float* __restrict__ w1,
    const float* __restrict__ w2, const float* __restrict__ w3,
    const float* __restrict__ norm1, const float* __restrict__ norm2,
    const float* __restrict__ normf, float* __restrict__ out,
    float* __restrict__ wsb) {
  __shared__ float lds[256 * 9];      // 9216 B
  __shared__ float scale[8];
  unsigned* cnt = (unsigned*)wsb;     // barrier counter (memset to 0 each launch)
  float* q    = wsb + 64;
  float* k    = wsb + 64 + 8192;
  float* v    = wsb + 64 + 16384;
  float* g    = wsb + 64 + 24576;
  float* xa   = wsb + 64 + 57344;
  float* xf   = wsb + 64 + 65536;
  float* ab   = wsb + 64 + 73728;
  float* pm   = wsb + 64 + 81920;
  float* ps   = wsb + 64 + 98304;
  float* pacc = wsb + 64 + 114688;
  const size_t WD = (size_t)DIM * DIM;
  const size_t WF = (size_t)4 * DIM * DIM;
  int bid = blockIdx.x, tid = threadIdx.x;
  unsigned bar = 0;

  for (int l = 0; l < LL; ++l) {
    const float* xin = (l == 0) ? x0 : xf;

    // ================= QKV GEMV + fused RMSNorm (3072 rows) =================
    {
      float4 xr[8];
#pragma unroll
      for (int bb = 0; bb < 8; ++bb)
        xr[bb] = *(const float4*)(xin + bb * DIM + tid * 4);
      rms_scales8(xr, lds, scale);
      float4 wn = *(const float4*)(norm1 + l * DIM + tid * 4);
#pragma unroll
      for (int bb = 0; bb < 8; ++bb) {
        xr[bb].x *= wn.x; xr[bb].y *= wn.y; xr[bb].z *= wn.z; xr[bb].w *= wn.w;
      }
      for (int row = bid; row < 3 * DIM; row += NBLK) {
        int mat = row >> 10, r = row & 1023;
        const float* W = (mat == 0 ? wq : mat == 1 ? wk : wv) + l * WD + (size_t)r * DIM;
        float4 w4 = *(const float4*)(W + tid * 4);
        float acc[8];
#pragma unroll
        for (int bb = 0; bb < 8; ++bb)
          acc[bb] = w4.x * xr[bb].x + w4.y * xr[bb].y + w4.z * xr[bb].z + w4.w * xr[bb].w;
        int bb; float s = block_reduce8(acc, lds, &bb);
        if ((tid & 31) == 0) {
          float* dst = (mat == 0 ? q : mat == 1 ? k : v);
          dst[bb * DIM + r] = s * scale[bb];
        }
      }
    }
    gsync(cnt, NBLK * (++bar));

    // ================= attention partials (NSPLIT x 64 units) =================
    {
      int grp = tid >> 5, lane = tid & 31;
      for (int u = bid; u < NSPLIT * 64; u += NBLK) {
        int c = u >> 6, bh = u & 63;
        int b = bh >> 3, hh = bh & 7;
        int ctx = ctxp[b];
        int CH = (ctx + NSPLIT - 1) / NSPLIT;
        int t0 = c * CH;
        int t1 = t0 + CH; if (t1 > ctx) t1 = ctx;
        int last = ctx - 1;
        const float4 q4 = *(const float4*)(q + b * DIM + hh * HD + lane * 4);
        const int* btb = bt + (size_t)l * BB * NB + b * NB;
        float m = -1e30f, ssum = 0.0f;
        float4 acc = make_float4(0.f, 0.f, 0.f, 0.f);
        for (int t = t0 + grp; t < t1; t += 8) {
          const float *Kp, *Vp;
          if (t == last) {
            Kp = k + b * DIM + hh * HD;
            Vp = v + b * DIM + hh * HD;
          } else {
            int pb = btb[t >> 4];
            size_t base = ((((size_t)pb * BS) + (t & 15)) * NH + hh) * HD;
            Kp = kheap + base;
            Vp = vheap + base;
          }
          float4 k4 = *(const float4*)(Kp + lane * 4);
          float4 v4 = *(const float4*)(Vp + lane * 4);
          float sc = q4.x * k4.x + q4.y * k4.y + q4.z * k4.z + q4.w * k4.w;
#pragma unroll
          for (int o = 16; o; o >>= 1) sc += __shfl_xor(sc, o);
          sc *= SCALE;
          float mnew = fmaxf(m, sc);
          float f = __expf(m - mnew);
          float p = __expf(sc - mnew);
          ssum = ssum * f + p;
          acc.x = acc.x * f + p * v4.x;
          acc.y = acc.y * f + p * v4.y;
          acc.z = acc.z * f + p * v4.z;
          acc.w = acc.w * f + p * v4.w;
          m = mnew;
        }
        int pi = bh * 256 + c * 8 + grp;
        if (lane == 0) { pm[pi] = m; ps[pi] = ssum; }
        *(float4*)(pacc + (size_t)pi * HD + lane * 4) = acc;
      }
    }
    gsync(cnt, NBLK * (++bar));

    // ================= attention reduce (64 units, 256 partials each) =================
    if (bid < 64) {
      int bh = bid;
      float* red = lds;           // 256 floats
      float* fb  = lds + 256;     // 256 floats
      float mi = pm[bh * 256 + tid];
      red[tid] = mi; __syncthreads();
#pragma unroll
      for (int o = 128; o; o >>= 1) {
        if (tid < o) red[tid] = fmaxf(red[tid], red[tid + o]);
        __syncthreads();
      }
      float M = red[0]; __syncthreads();
      float fi = __expf(mi - M);
      fb[tid] = fi;
      red[tid] = ps[bh * 256 + tid] * fi;
      __syncthreads();
#pragma unroll
      for (int o = 128; o; o >>= 1) {
        if (tid < o) red[tid] += red[tid + o];
        __syncthreads();
      }
      float inv = 1.0f / red[0];
      int d = tid & 127, hp = tid >> 7;
      float od = 0.0f;
      const float* pb = pacc + ((size_t)bh * 256 + hp * 128) * HD + d;
      for (int p = 0; p < 128; ++p) od += pb[(size_t)p * HD] * fb[hp * 128 + p];
      __syncthreads();
      red[tid] = od; __syncthreads();
      if (tid < 128) ab[bh * HD + tid] = (red[tid] + red[tid + 128]) * inv;
    }
    gsync(cnt, NBLK * (++bar));

    // ================= o-proj + residual (1024 rows) =================
    for (int r = bid; r < DIM; r += NBLK) {
      float4 w4 = *(const float4*)(wo + l * WD + (size_t)r * DIM + tid * 4);
      float acc[8];
#pragma unroll
      for (int bb = 0; bb < 8; ++bb) {
        float4 h4 = *(const float4*)(ab + bb * DIM + tid * 4);
        acc[bb] = w4.x * h4.x + w4.y * h4.y + w4.z * h4.z + w4.w * h4.w;
      }
      int bb; float s = block_reduce8(acc, lds, &bb);
      if ((tid & 31) == 0) xa[bb * DIM + r] = s + xin[bb * DIM + r];
    }
    gsync(cnt, NBLK * (++bar));

    // ================= FFN w1/w3 + SwiGLU + fused RMSNorm (4096 rows) =================
    {
      float4 xr[8];
#pragma unroll
      for (int bb = 0; bb < 8; ++bb)
        xr[bb] = *(const float4*)(xa + bb * DIM + tid * 4);
      rms_scales8(xr, lds, scale);
      float4 wn = *(const float4*)(norm2 + l * DIM + tid * 4);
#pragma unroll
      for (int bb = 0; bb < 8; ++bb) {
        xr[bb].x *= wn.x; xr[bb].y *= wn.y; xr[bb].z *= wn.z; xr[bb].w *= wn.w;
      }
      for (int r = bid; r < 4 * DIM; r += NBLK) {
        float4 w14 = *(const float4*)(w1 + l * WF + (size_t)r * DIM + tid * 4);
        float4 w34 = *(const float4*)(w3 + l * WF + (size_t)r * DIM + tid * 4);
        float a[8], c[8];
#pragma unroll
        for (int bb = 0; bb < 8; ++bb) {
          a[bb] = w14.x * xr[bb].x + w14.y * xr[bb].y + w14.z * xr[bb].z + w14.w * xr[bb].w;
          c[bb] = w34.x * xr[bb].x + w34.y * xr[bb].y + w34.z * xr[bb].z + w34.w * xr[bb].w;
        }
        int bb;
        float sa = block_reduce8(a, lds, &bb);
        float sc = block_reduce8(c, lds, &bb);
        if ((tid & 31) == 0) {
          float sv = sa * scale[bb];
          sv = sv / (1.0f + __expf(-sv));      // silu
          g[bb * 4 * DIM + r] = sv * (sc * scale[bb]);
        }
      }
    }
    gsync(cnt, NBLK * (++bar));

    // ================= FFN w2 + residual (1024 rows, K=4096) =================
    for (int r = bid; r < DIM; r += NBLK) {
      const float* W = w2 + l * WF + (size_t)r * 4 * DIM;
      float acc[8] = {};
#pragma unroll
      for (int j4 = 0; j4 < 4; ++j4) {
        int j = j4 * 1024 + tid * 4;
        float4 w4 = *(const float4*)(W + j);
#pragma unroll
        for (int bb = 0; bb < 8; ++bb) {
          float4 g4 = *(const float4*)(g + bb * 4 * DIM + j);
          acc[bb] += w4.x * g4.x + w4.y * g4.y + w4.z * g4.z + w4.w * g4.w;
        }
      }
      int bb; float s = block_reduce8(acc, lds, &bb);
      if ((tid & 31) == 0) xf[bb * DIM + r] = s + xa[bb * DIM + r];
    }
    gsync(cnt, NBLK * (++bar));
  }

  // ================= final RMSNorm (8 rows) =================
  if (bid < BB) {
    int b = bid;
    float4 vv = ((const float4*)(xf + (size_t)b * DIM))[tid];
    float s = vv.x * vv.x + vv.y * vv.y + vv.z * vv.z + vv.w * vv.w;
#pragma unroll
    for (int o = 32; o; o >>= 1) s += __shfl_xor(s, o);
    if ((tid & 63) == 0) lds[tid >> 6] = s;
    __syncthreads();
    float tot = lds[0] + lds[1] + lds[2] + lds[3];
    float r = rsqrtf(tot * (1.0f / DIM) + EPS);
    float4 wv4 = ((const float4*)normf)[tid];
    float4 o4;
    o4.x = vv.x * r * wv4.x; o4.y = vv.y * r * wv4.y;
    o4.z = vv.z * r * wv4.z; o4.w = vv.w * r * wv4.w;
    ((float4*)(out + (size_t)b * DIM))[tid] = o4;
  }
}

extern "C" void kernel_launch(void* const* d_in, const int* in_sizes, int n_in,
                              void* d_out, int out_size, void* d_ws, size_t ws_size,
                              hipStream_t stream) {
  const float* x0    = (const float*)d_in[0];
  const float* kheap = (const float*)d_in[1];
  const float* vheap = (const float*)d_in[2];
  const int*   bt    = (const int*)d_in[3];
  // d_in[4] = slot_mapping (int64) — unused; derived from context_lens instead.
  const int*   ctx   = (const int*)d_in[5];
  const float* wq    = (const float*)d_in[6];
  const float* wk    = (const float*)d_in[7];
  const float* wv    = (const float*)d_in[8];
  const float* wo    = (const float*)d_in[9];
  const float* w1    = (const float*)d_in[10];
  const float* w2    = (const float*)d_in[11];
  const float* w3    = (const float*)d_in[12];
  const float* norm1 = (const float*)d_in[13];
  const float* norm2 = (const float*)d_in[14];
  const float* normf = (const float*)d_in[15];

  // zero the barrier counter (graph-legal memset node, replayed each call)
  hipMemsetAsync(d_ws, 0, 256, stream);

  mega_k<<<NBLK, 256, 0, stream>>>(x0, kheap, vheap, bt, ctx, wq, wk, wv, wo,
                                   w1, w2, w3, norm1, norm2, normf,
                                   (float*)d_out, (float*)d_ws);
}

// Round 8
// 379.252 us; speedup vs baseline: 6.1962x; 3.3374x over previous
//
#include <hip/hip_runtime.h>

#define BB    8
#define LL    2
#define DIM   1024
#define NH    8
#define HD    128
#define BS    16
#define NB    129
#define NSPLIT 32
#define SCALE 0.08838834764831845f   // 1/sqrt(128)
#define EPS   1e-5f

__device__ __forceinline__ float wave_reduce_add(float v) {
#pragma unroll
  for (int o = 32; o; o >>= 1) v += __shfl_xor(v, o);
  return v;
}

// ---- in-block rms scales: from 8 per-thread partials -> scale[8] in LDS ----
__device__ __forceinline__ void block_rms_scales(const float ss[8], float* lds,
                                                 float* scale) {
  int tid = threadIdx.x;
#pragma unroll
  for (int b = 0; b < 8; ++b) lds[tid * 9 + b] = ss[b];
  __syncthreads();
  int bb = tid >> 5, i = tid & 31;
  float s = 0.0f;
#pragma unroll
  for (int j = 0; j < 8; ++j) s += lds[(i + 32 * j) * 9 + bb];
#pragma unroll
  for (int o = 16; o; o >>= 1) s += __shfl_xor(s, o);
  if (i == 0) scale[bb] = rsqrtf(s * (1.0f / DIM) + EPS);
  __syncthreads();
}

// ---- LDS-transpose block reduce of 8 accumulators ----
__device__ __forceinline__ float block_reduce8(const float acc[8], float* lds,
                                               int* bb_out) {
  int tid = threadIdx.x;
#pragma unroll
  for (int b = 0; b < 8; ++b) lds[tid * 9 + b] = acc[b];
  __syncthreads();
  int bb = tid >> 5, i = tid & 31;
  float s = 0.0f;
#pragma unroll
  for (int j = 0; j < 8; ++j) s += lds[(i + 32 * j) * 9 + bb];
#pragma unroll
  for (int o = 16; o; o >>= 1) s += __shfl_xor(s, o);
  __syncthreads();
  *bb_out = bb;
  return s;
}

// ------ QKV GEMV with fused RMSNorm: one block per output row (3072 rows) ------
__global__ void qkv_k(const float* __restrict__ x, const float* __restrict__ nw,
                      const float* __restrict__ wq, const float* __restrict__ wk,
                      const float* __restrict__ wv,
                      float* __restrict__ q, float* __restrict__ k, float* __restrict__ v) {
  __shared__ float lds[256 * 9];
  __shared__ float scale[8];
  int tid = threadIdx.x;
  float4 xr[8];
  float ss[8];
#pragma unroll
  for (int bb = 0; bb < 8; ++bb) {
    xr[bb] = *(const float4*)(x + bb * DIM + tid * 4);
    ss[bb] = xr[bb].x * xr[bb].x + xr[bb].y * xr[bb].y +
             xr[bb].z * xr[bb].z + xr[bb].w * xr[bb].w;
  }
  block_rms_scales(ss, lds, scale);

  int row = blockIdx.x;                  // 0..3071
  int mat = row >> 10, r = row & 1023;
  const float* W = (mat == 0 ? wq : mat == 1 ? wk : wv) + (size_t)r * DIM;
  float4 wn = *(const float4*)(nw + tid * 4);
  float4 w4 = *(const float4*)(W + tid * 4);
  float acc[8];
#pragma unroll
  for (int bb = 0; bb < 8; ++bb) {
    acc[bb] = w4.x * (xr[bb].x * wn.x) + w4.y * (xr[bb].y * wn.y) +
              w4.z * (xr[bb].z * wn.z) + w4.w * (xr[bb].w * wn.w);
  }
  int bb; float s = block_reduce8(acc, lds, &bb);
  if ((tid & 31) == 0) {
    float* dst = (mat == 0 ? q : mat == 1 ? k : v);
    dst[bb * DIM + r] = s * scale[bb];
  }
}

// ------ flash-decode partial + last-block-done reduce: grid (NSPLIT, B*H) ------
__global__ void attn_partial_k(const float* __restrict__ qb, const float* __restrict__ kb,
                               const float* __restrict__ vb,
                               const float* __restrict__ kheap, const float* __restrict__ vheap,
                               const int* __restrict__ bt, const int* __restrict__ ctx_lens,
                               float* __restrict__ pm, float* __restrict__ ps,
                               float* __restrict__ pacc, float* __restrict__ ab,
                               unsigned* __restrict__ done) {
  int c  = blockIdx.x;
  int bh = blockIdx.y;
  int b = bh >> 3, hh = bh & 7;
  int tid = threadIdx.x;
  int grp = tid >> 5, lane = tid & 31;
  int ctx = ctx_lens[b];
  int CH = (ctx + NSPLIT - 1) / NSPLIT;
  int t0 = c * CH;
  int t1 = t0 + CH; if (t1 > ctx) t1 = ctx;
  int last = ctx - 1;
  const float4 q4 = *(const float4*)(qb + (size_t)b * DIM + hh * HD + lane * 4);
  const int* btb = bt + b * NB;
  float m = -1e30f, ssum = 0.0f;
  float4 acc = make_float4(0.f, 0.f, 0.f, 0.f);
  for (int t = t0 + grp; t < t1; t += 8) {
    const float *Kp, *Vp;
    if (t == last) {
      Kp = kb + (size_t)b * DIM + hh * HD;
      Vp = vb + (size_t)b * DIM + hh * HD;
    } else {
      int pb = btb[t >> 4];
      size_t base = ((((size_t)pb * BS) + (t & 15)) * NH + hh) * HD;
      Kp = kheap + base;
      Vp = vheap + base;
    }
    float4 k4 = *(const float4*)(Kp + lane * 4);
    float4 v4 = *(const float4*)(Vp + lane * 4);
    float sc = q4.x * k4.x + q4.y * k4.y + q4.z * k4.z + q4.w * k4.w;
#pragma unroll
    for (int o = 16; o; o >>= 1) sc += __shfl_xor(sc, o);
    sc *= SCALE;
    float mnew = fmaxf(m, sc);
    float f = __expf(m - mnew);
    float p = __expf(sc - mnew);
    ssum = ssum * f + p;
    acc.x = acc.x * f + p * v4.x;
    acc.y = acc.y * f + p * v4.y;
    acc.z = acc.z * f + p * v4.z;
    acc.w = acc.w * f + p * v4.w;
    m = mnew;
  }
  int pi = bh * 256 + c * 8 + grp;
  if (lane == 0) { pm[pi] = m; ps[pi] = ssum; }
  *(float4*)(pacc + (size_t)pi * HD + lane * 4) = acc;

  // ---- last-block-done reduction for this bh ----
  __shared__ int lastflag;
  __shared__ float red[256];
  __shared__ float fb[256];
  __syncthreads();                       // all stores of this block issued & drained
  if (tid == 0) {
    __threadfence();                     // release: write back this XCD's L2
    unsigned old = atomicAdd(&done[bh], 1u);
    lastflag = (old == NSPLIT - 1);
  }
  __syncthreads();
  if (lastflag) {
    if (tid == 0) __threadfence();       // acquire: invalidate stale L1/L2 lines
    __syncthreads();
    float mi = pm[bh * 256 + tid];
    red[tid] = mi; __syncthreads();
#pragma unroll
    for (int o = 128; o; o >>= 1) {
      if (tid < o) red[tid] = fmaxf(red[tid], red[tid + o]);
      __syncthreads();
    }
    float M = red[0]; __syncthreads();
    float fi = __expf(mi - M);
    fb[tid] = fi;
    red[tid] = ps[bh * 256 + tid] * fi;
    __syncthreads();
#pragma unroll
    for (int o = 128; o; o >>= 1) {
      if (tid < o) red[tid] += red[tid + o];
      __syncthreads();
    }
    float inv = 1.0f / red[0];
    int d = tid & 127, hp = tid >> 7;
    float od = 0.0f;
    const float* pb2 = pacc + ((size_t)bh * 256 + hp * 128) * HD + d;
    for (int p = 0; p < 128; ++p) od += pb2[(size_t)p * HD] * fb[hp * 128 + p];
    __syncthreads();
    red[tid] = od; __syncthreads();
    if (tid < 128) ab[bh * HD + tid] = (red[tid] + red[tid + 128]) * inv;
  }
}

// -------------------- o-proj GEMV + residual: one block per row --------------------
__global__ void proj_res_k(const float* __restrict__ in, const float* __restrict__ W0,
                           const float* __restrict__ resid, float* __restrict__ out) {
  __shared__ float lds[256 * 9];
  int r = blockIdx.x;                    // 0..1023
  int tid = threadIdx.x;
  float4 w4 = *(const float4*)(W0 + (size_t)r * DIM + tid * 4);
  float acc[8];
#pragma unroll
  for (int bb = 0; bb < 8; ++bb) {
    float4 h4 = *(const float4*)(in + bb * DIM + tid * 4);
    acc[bb] = w4.x * h4.x + w4.y * h4.y + w4.z * h4.z + w4.w * h4.w;
  }
  int bb; float s = block_reduce8(acc, lds, &bb);
  if ((tid & 31) == 0) out[bb * DIM + r] = s + resid[bb * DIM + r];
}

// ------ FFN w1/w3 + SwiGLU with fused RMSNorm: one block per row (4096 rows) ------
__global__ void ffn13_k(const float* __restrict__ xa, const float* __restrict__ nw,
                        const float* __restrict__ w1, const float* __restrict__ w3,
                        float* __restrict__ g) {
  __shared__ float ldsA[256 * 9];
  __shared__ float ldsC[256 * 9];
  __shared__ float scale[8];
  int tid = threadIdx.x;
  float4 xr[8];
  float ss[8];
#pragma unroll
  for (int bb = 0; bb < 8; ++bb) {
    xr[bb] = *(const float4*)(xa + bb * DIM + tid * 4);
    ss[bb] = xr[bb].x * xr[bb].x + xr[bb].y * xr[bb].y +
             xr[bb].z * xr[bb].z + xr[bb].w * xr[bb].w;
  }
  block_rms_scales(ss, ldsA, scale);

  int r = blockIdx.x;                    // 0..4095
  float4 wn = *(const float4*)(nw + tid * 4);
  float4 w14 = *(const float4*)(w1 + (size_t)r * DIM + tid * 4);
  float4 w34 = *(const float4*)(w3 + (size_t)r * DIM + tid * 4);
  float a[8], c[8];
#pragma unroll
  for (int bb = 0; bb < 8; ++bb) {
    float hx = xr[bb].x * wn.x, hy = xr[bb].y * wn.y;
    float hz = xr[bb].z * wn.z, hw = xr[bb].w * wn.w;
    a[bb] = w14.x * hx + w14.y * hy + w14.z * hz + w14.w * hw;
    c[bb] = w34.x * hx + w34.y * hy + w34.z * hz + w34.w * hw;
  }
#pragma unroll
  for (int b = 0; b < 8; ++b) { ldsA[tid * 9 + b] = a[b]; ldsC[tid * 9 + b] = c[b]; }
  __syncthreads();
  int bb = tid >> 5, i = tid & 31;
  float sa = 0.0f, sc = 0.0f;
#pragma unroll
  for (int j = 0; j < 8; ++j) {
    sa += ldsA[(i + 32 * j) * 9 + bb];
    sc += ldsC[(i + 32 * j) * 9 + bb];
  }
#pragma unroll
  for (int o = 16; o; o >>= 1) { sa += __shfl_xor(sa, o); sc += __shfl_xor(sc, o); }
  if (i == 0) {
    float sv = sa * scale[bb];
    sv = sv / (1.0f + __expf(-sv));      // silu
    g[bb * 4 * DIM + r] = sv * (sc * scale[bb]);
  }
}

// ------ FFN w2 + residual (K=4096), optional fused final RMSNorm tail ------
__global__ void ffn2_k(const float* __restrict__ g, const float* __restrict__ w2,
                       const float* __restrict__ resid, float* __restrict__ out,
                       const float* __restrict__ normf, float* __restrict__ fout,
                       unsigned* __restrict__ done2, int dofinal) {
  __shared__ float lds[256 * 9];
  int r = blockIdx.x;                    // 0..1023
  int tid = threadIdx.x;
  const float* W = w2 + (size_t)r * 4 * DIM;
  float acc[8] = {};
#pragma unroll
  for (int j4 = 0; j4 < 4; ++j4) {
    int j = j4 * 1024 + tid * 4;
    float4 w4 = *(const float4*)(W + j);
#pragma unroll
    for (int bb = 0; bb < 8; ++bb) {
      float4 g4 = *(const float4*)(g + bb * 4 * DIM + j);
      acc[bb] += w4.x * g4.x + w4.y * g4.y + w4.z * g4.z + w4.w * g4.w;
    }
  }
  int bb; float s = block_reduce8(acc, lds, &bb);
  if ((tid & 31) == 0) out[bb * DIM + r] = s + resid[bb * DIM + r];

  if (dofinal) {
    __shared__ int lastf;
    __shared__ float wsum[4];
    __syncthreads();
    if (tid == 0) {
      __threadfence();                   // release
      unsigned old = atomicAdd(done2, 1u);
      lastf = (old == DIM - 1);
    }
    __syncthreads();
    if (lastf) {
      if (tid == 0) __threadfence();     // acquire
      __syncthreads();
      for (int b = 0; b < BB; ++b) {
        float4 vv = ((const float4*)(out + (size_t)b * DIM))[tid];
        float ssq = vv.x * vv.x + vv.y * vv.y + vv.z * vv.z + vv.w * vv.w;
        ssq = wave_reduce_add(ssq);
        if ((tid & 63) == 0) wsum[tid >> 6] = ssq;
        __syncthreads();
        float tot = wsum[0] + wsum[1] + wsum[2] + wsum[3];
        float rr = rsqrtf(tot * (1.0f / DIM) + EPS);
        float4 wn = ((const float4*)normf)[tid];
        float4 o4;
        o4.x = vv.x * rr * wn.x; o4.y = vv.y * rr * wn.y;
        o4.z = vv.z * rr * wn.z; o4.w = vv.w * rr * wn.w;
        ((float4*)(fout + (size_t)b * DIM))[tid] = o4;
        __syncthreads();
      }
    }
  }
}

extern "C" void kernel_launch(void* const* d_in, const int* in_sizes, int n_in,
                              void* d_out, int out_size, void* d_ws, size_t ws_size,
                              hipStream_t stream) {
  const float* x0    = (const float*)d_in[0];
  const float* kheap = (const float*)d_in[1];
  const float* vheap = (const float*)d_in[2];
  const int*   bt    = (const int*)d_in[3];
  // d_in[4] = slot_mapping (int64) — unused; derived from context_lens instead.
  const int*   ctx   = (const int*)d_in[5];
  const float* wq    = (const float*)d_in[6];
  const float* wk    = (const float*)d_in[7];
  const float* wv    = (const float*)d_in[8];
  const float* wo    = (const float*)d_in[9];
  const float* w1    = (const float*)d_in[10];
  const float* w2    = (const float*)d_in[11];
  const float* w3    = (const float*)d_in[12];
  const float* norm1 = (const float*)d_in[13];
  const float* norm2 = (const float*)d_in[14];
  const float* normf = (const float*)d_in[15];

  float* ws = (float*)d_ws;
  unsigned* done  = (unsigned*)d_ws;     // [0..127]: attn done (2 layers x 64)
  unsigned* done2 = done + 128;          // [128]: ffn2-final done
  float* q    = ws + 256;            // 8192
  float* k    = ws + 8448;           // 8192
  float* v    = ws + 16640;          // 8192
  float* g    = ws + 24832;          // 32768
  float* xa   = ws + 57600;          // 8192
  float* xf   = ws + 65792;          // 8192
  float* ab   = ws + 73984;          // 8192
  float* pm   = ws + 82176;          // 16384
  float* ps   = ws + 98560;          // 16384
  float* pacc = ws + 114944;         // 64*256*128 = 2097152 floats

  const size_t WD = (size_t)DIM * DIM;
  const size_t WF = (size_t)4 * DIM * DIM;

  hipMemsetAsync(d_ws, 0, 1024, stream);   // zero done counters (graph-legal)

  for (int l = 0; l < LL; ++l) {
    const float* xin = (l == 0) ? x0 : xf;
    qkv_k<<<3072, 256, 0, stream>>>(xin, norm1 + l * DIM,
                                    wq + l * WD, wk + l * WD, wv + l * WD, q, k, v);
    attn_partial_k<<<dim3(NSPLIT, BB * NH), 256, 0, stream>>>(
        q, k, v, kheap, vheap, bt + l * BB * NB, ctx, pm, ps, pacc, ab, done + l * 64);
    proj_res_k<<<1024, 256, 0, stream>>>(ab, wo + l * WD, xin, xa);
    ffn13_k<<<4096, 256, 0, stream>>>(xa, norm2 + l * DIM, w1 + l * WF, w3 + l * WF, g);
    ffn2_k<<<1024, 256, 0, stream>>>(g, w2 + l * WF, xa, xf,
                                     normf, (float*)d_out, done2, (l == LL - 1) ? 1 : 0);
  }
}

// Round 9
// 148.873 us; speedup vs baseline: 15.7848x; 2.5475x over previous
//
#include <hip/hip_runtime.h>

#define BB    8
#define LL    2
#define DIM   1024
#define NH    8
#define HD    128
#define BS    16
#define NB    129
#define NSPLIT 32
#define SCALE 0.08838834764831845f   // 1/sqrt(128)
#define EPS   1e-5f

// ---- online-softmax single-token update ----
#define OS_UPDATE(mm, sss, AA, sc, v4) {          \
    float mnew = fmaxf(mm, sc);                   \
    float fo = __expf(mm - mnew);                 \
    float pr = __expf(sc - mnew);                 \
    sss = sss * fo + pr;                          \
    AA.x = AA.x * fo + pr * v4.x;                 \
    AA.y = AA.y * fo + pr * v4.y;                 \
    AA.z = AA.z * fo + pr * v4.z;                 \
    AA.w = AA.w * fo + pr * v4.w;                 \
    mm = mnew; }

// -------------------- final RMSNorm: one block per batch row --------------------
__global__ void rmsnorm_k(const float* __restrict__ x, const float* __restrict__ w,
                          float* __restrict__ out) {
  int b = blockIdx.x;
  float4 v = ((const float4*)(x + (size_t)b * DIM))[threadIdx.x];
  float s = v.x * v.x + v.y * v.y + v.z * v.z + v.w * v.w;
#pragma unroll
  for (int o = 32; o; o >>= 1) s += __shfl_xor(s, o);
  __shared__ float wsum[4];
  int wid = threadIdx.x >> 6;
  if ((threadIdx.x & 63) == 0) wsum[wid] = s;
  __syncthreads();
  float tot = wsum[0] + wsum[1] + wsum[2] + wsum[3];
  float r = rsqrtf(tot * (1.0f / DIM) + EPS);
  float4 wv = ((const float4*)w)[threadIdx.x];
  float4 o;
  o.x = v.x * r * wv.x; o.y = v.y * r * wv.y;
  o.z = v.z * r * wv.z; o.w = v.w * r * wv.w;
  ((float4*)(out + (size_t)b * DIM))[threadIdx.x] = o;
}

// ---- in-block rms scales: from 8 per-thread partials -> scale[8] in LDS ----
__device__ __forceinline__ void block_rms_scales(const float ss[8], float* lds,
                                                 float* scale) {
  int tid = threadIdx.x;
#pragma unroll
  for (int b = 0; b < 8; ++b) lds[tid * 9 + b] = ss[b];
  __syncthreads();
  int bb = tid >> 5, i = tid & 31;
  float s = 0.0f;
#pragma unroll
  for (int j = 0; j < 8; ++j) s += lds[(i + 32 * j) * 9 + bb];
#pragma unroll
  for (int o = 16; o; o >>= 1) s += __shfl_xor(s, o);
  if (i == 0) scale[bb] = rsqrtf(s * (1.0f / DIM) + EPS);
  __syncthreads();
}

// ---- LDS-transpose block reduce of 8 accumulators ----
__device__ __forceinline__ float block_reduce8(const float acc[8], float* lds,
                                               int* bb_out) {
  int tid = threadIdx.x;
#pragma unroll
  for (int b = 0; b < 8; ++b) lds[tid * 9 + b] = acc[b];
  __syncthreads();
  int bb = tid >> 5, i = tid & 31;
  float s = 0.0f;
#pragma unroll
  for (int j = 0; j < 8; ++j) s += lds[(i + 32 * j) * 9 + bb];
#pragma unroll
  for (int o = 16; o; o >>= 1) s += __shfl_xor(s, o);
  __syncthreads();
  *bb_out = bb;
  return s;
}

// ------ QKV GEMV with fused RMSNorm: one block per output row (3072 rows) ------
__global__ void qkv_k(const float* __restrict__ x, const float* __restrict__ nw,
                      const float* __restrict__ wq, const float* __restrict__ wk,
                      const float* __restrict__ wv,
                      float* __restrict__ q, float* __restrict__ k, float* __restrict__ v) {
  __shared__ float lds[256 * 9];
  __shared__ float scale[8];
  int tid = threadIdx.x;
  float4 xr[8];
  float ss[8];
#pragma unroll
  for (int bb = 0; bb < 8; ++bb) {
    xr[bb] = *(const float4*)(x + bb * DIM + tid * 4);
    ss[bb] = xr[bb].x * xr[bb].x + xr[bb].y * xr[bb].y +
             xr[bb].z * xr[bb].z + xr[bb].w * xr[bb].w;
  }
  block_rms_scales(ss, lds, scale);

  int row = blockIdx.x;                  // 0..3071
  int mat = row >> 10, r = row & 1023;
  const float* W = (mat == 0 ? wq : mat == 1 ? wk : wv) + (size_t)r * DIM;
  float4 wn = *(const float4*)(nw + tid * 4);
  float4 w4 = *(const float4*)(W + tid * 4);
  float acc[8];
#pragma unroll
  for (int bb = 0; bb < 8; ++bb) {
    acc[bb] = w4.x * (xr[bb].x * wn.x) + w4.y * (xr[bb].y * wn.y) +
              w4.z * (xr[bb].z * wn.z) + w4.w * (xr[bb].w * wn.w);
  }
  int bb; float s = block_reduce8(acc, lds, &bb);
  if ((tid & 31) == 0) {
    float* dst = (mat == 0 ? q : mat == 1 ? k : v);
    dst[bb * DIM + r] = s * scale[bb];
  }
}

// ------ flash-decode partial, ILP-2: grid (NSPLIT, B*H), 8 half-wave groups ------
__global__ void attn_partial_k(const float* __restrict__ qb, const float* __restrict__ kb,
                               const float* __restrict__ vb,
                               const float* __restrict__ kheap, const float* __restrict__ vheap,
                               const int* __restrict__ bt, const int* __restrict__ ctx_lens,
                               float* __restrict__ pm, float* __restrict__ ps,
                               float* __restrict__ pacc) {
  int c  = blockIdx.x;
  int bh = blockIdx.y;
  int b = bh >> 3, hh = bh & 7;
  int tid = threadIdx.x;
  int grp = tid >> 5, lane = tid & 31;
  int ctx = ctx_lens[b];
  int CH = (ctx + NSPLIT - 1) / NSPLIT;
  int t0 = c * CH;
  int t1 = t0 + CH; if (t1 > ctx) t1 = ctx;
  bool hasNew = (t1 == ctx);             // this unit owns the new token (pos ctx-1)
  int tlim = hasNew ? ctx - 1 : t1;      // heap tokens are in [t0, tlim)
  const float4 q4 = *(const float4*)(qb + (size_t)b * DIM + hh * HD + lane * 4);
  const int* btb = bt + b * NB;

  // two independent online-softmax chains per group
  float m0 = -1e30f, m1 = -1e30f, s0 = 0.0f, s1 = 0.0f;
  float4 A0 = make_float4(0.f, 0.f, 0.f, 0.f);
  float4 A1 = make_float4(0.f, 0.f, 0.f, 0.f);

  int t = t0 + grp;
  for (; t + 8 < tlim; t += 16) {
    int ta = t, tb2 = t + 8;
    size_t base0 = ((((size_t)btb[ta >> 4] * BS) + (ta & 15)) * NH + hh) * HD;
    size_t base1 = ((((size_t)btb[tb2 >> 4] * BS) + (tb2 & 15)) * NH + hh) * HD;
    float4 k0 = *(const float4*)(kheap + base0 + lane * 4);
    float4 k1 = *(const float4*)(kheap + base1 + lane * 4);
    float4 v0 = *(const float4*)(vheap + base0 + lane * 4);
    float4 v1 = *(const float4*)(vheap + base1 + lane * 4);
    float sc0 = q4.x * k0.x + q4.y * k0.y + q4.z * k0.z + q4.w * k0.w;
    float sc1 = q4.x * k1.x + q4.y * k1.y + q4.z * k1.z + q4.w * k1.w;
#pragma unroll
    for (int o = 16; o; o >>= 1) {
      sc0 += __shfl_xor(sc0, o);
      sc1 += __shfl_xor(sc1, o);
    }
    sc0 *= SCALE; sc1 *= SCALE;
    OS_UPDATE(m0, s0, A0, sc0, v0);
    OS_UPDATE(m1, s1, A1, sc1, v1);
  }
  for (; t < tlim; t += 8) {             // at most one leftover heap token
    size_t base0 = ((((size_t)btb[t >> 4] * BS) + (t & 15)) * NH + hh) * HD;
    float4 k0 = *(const float4*)(kheap + base0 + lane * 4);
    float4 v0 = *(const float4*)(vheap + base0 + lane * 4);
    float sc0 = q4.x * k0.x + q4.y * k0.y + q4.z * k0.z + q4.w * k0.w;
#pragma unroll
    for (int o = 16; o; o >>= 1) sc0 += __shfl_xor(sc0, o);
    sc0 *= SCALE;
    OS_UPDATE(m0, s0, A0, sc0, v0);
  }
  if (hasNew && ((ctx - 1 - t0) & 7) == grp) {   // new token from fresh k/v buffers
    float4 k0 = *(const float4*)(kb + (size_t)b * DIM + hh * HD + lane * 4);
    float4 v0 = *(const float4*)(vb + (size_t)b * DIM + hh * HD + lane * 4);
    float sc0 = q4.x * k0.x + q4.y * k0.y + q4.z * k0.z + q4.w * k0.w;
#pragma unroll
    for (int o = 16; o; o >>= 1) sc0 += __shfl_xor(sc0, o);
    sc0 *= SCALE;
    OS_UPDATE(m0, s0, A0, sc0, v0);
  }

  // merge the two chains
  float M = fmaxf(m0, m1);
  float f0 = __expf(m0 - M), f1 = __expf(m1 - M);
  float ssum = s0 * f0 + s1 * f1;
  float4 acc;
  acc.x = A0.x * f0 + A1.x * f1;
  acc.y = A0.y * f0 + A1.y * f1;
  acc.z = A0.z * f0 + A1.z * f1;
  acc.w = A0.w * f0 + A1.w * f1;

  int pi = bh * 256 + c * 8 + grp;
  if (lane == 0) { pm[pi] = M; ps[pi] = ssum; }
  *(float4*)(pacc + (size_t)pi * HD + lane * 4) = acc;
}

// ------ flash-decode reduce: one block per (b,h), 256 threads, 256 partials ------
__global__ void attn_reduce_k(const float* __restrict__ pm, const float* __restrict__ ps,
                              const float* __restrict__ pacc, float* __restrict__ ab) {
  int bh = blockIdx.x;
  int tid = threadIdx.x;   // 0..255
  __shared__ float red[256];
  __shared__ float fb[256];
  float mi = pm[bh * 256 + tid];
  red[tid] = mi; __syncthreads();
#pragma unroll
  for (int o = 128; o; o >>= 1) {
    if (tid < o) red[tid] = fmaxf(red[tid], red[tid + o]);
    __syncthreads();
  }
  float M = red[0]; __syncthreads();
  float fi = __expf(mi - M);
  fb[tid] = fi;
  red[tid] = ps[bh * 256 + tid] * fi;
  __syncthreads();
#pragma unroll
  for (int o = 128; o; o >>= 1) {
    if (tid < o) red[tid] += red[tid + o];
    __syncthreads();
  }
  float inv = 1.0f / red[0];
  int d = tid & 127, hp = tid >> 7;
  float od = 0.0f;
  const float* pb2 = pacc + ((size_t)bh * 256 + hp * 128) * HD + d;
  for (int p = 0; p < 128; ++p) od += pb2[(size_t)p * HD] * fb[hp * 128 + p];
  __syncthreads();
  red[tid] = od; __syncthreads();
  if (tid < 128) ab[bh * HD + tid] = (red[tid] + red[tid + 128]) * inv;
}

// -------------------- o-proj GEMV + residual: one block per row --------------------
__global__ void proj_res_k(const float* __restrict__ in, const float* __restrict__ W0,
                           const float* __restrict__ resid, float* __restrict__ out) {
  __shared__ float lds[256 * 9];
  int r = blockIdx.x;                    // 0..1023
  int tid = threadIdx.x;
  float4 w4 = *(const float4*)(W0 + (size_t)r * DIM + tid * 4);
  float acc[8];
#pragma unroll
  for (int bb = 0; bb < 8; ++bb) {
    float4 h4 = *(const float4*)(in + bb * DIM + tid * 4);
    acc[bb] = w4.x * h4.x + w4.y * h4.y + w4.z * h4.z + w4.w * h4.w;
  }
  int bb; float s = block_reduce8(acc, lds, &bb);
  if ((tid & 31) == 0) out[bb * DIM + r] = s + resid[bb * DIM + r];
}

// ------ FFN w1/w3 + SwiGLU with fused RMSNorm: one block per row (4096 rows) ------
__global__ void ffn13_k(const float* __restrict__ xa, const float* __restrict__ nw,
                        const float* __restrict__ w1, const float* __restrict__ w3,
                        float* __restrict__ g) {
  __shared__ float ldsA[256 * 9];
  __shared__ float ldsC[256 * 9];
  __shared__ float scale[8];
  int tid = threadIdx.x;
  float4 xr[8];
  float ss[8];
#pragma unroll
  for (int bb = 0; bb < 8; ++bb) {
    xr[bb] = *(const float4*)(xa + bb * DIM + tid * 4);
    ss[bb] = xr[bb].x * xr[bb].x + xr[bb].y * xr[bb].y +
             xr[bb].z * xr[bb].z + xr[bb].w * xr[bb].w;
  }
  block_rms_scales(ss, ldsA, scale);

  int r = blockIdx.x;                    // 0..4095
  float4 wn = *(const float4*)(nw + tid * 4);
  float4 w14 = *(const float4*)(w1 + (size_t)r * DIM + tid * 4);
  float4 w34 = *(const float4*)(w3 + (size_t)r * DIM + tid * 4);
  float a[8], c[8];
#pragma unroll
  for (int bb = 0; bb < 8; ++bb) {
    float hx = xr[bb].x * wn.x, hy = xr[bb].y * wn.y;
    float hz = xr[bb].z * wn.z, hw = xr[bb].w * wn.w;
    a[bb] = w14.x * hx + w14.y * hy + w14.z * hz + w14.w * hw;
    c[bb] = w34.x * hx + w34.y * hy + w34.z * hz + w34.w * hw;
  }
#pragma unroll
  for (int b = 0; b < 8; ++b) { ldsA[tid * 9 + b] = a[b]; ldsC[tid * 9 + b] = c[b]; }
  __syncthreads();
  int bb = tid >> 5, i = tid & 31;
  float sa = 0.0f, sc = 0.0f;
#pragma unroll
  for (int j = 0; j < 8; ++j) {
    sa += ldsA[(i + 32 * j) * 9 + bb];
    sc += ldsC[(i + 32 * j) * 9 + bb];
  }
#pragma unroll
  for (int o = 16; o; o >>= 1) { sa += __shfl_xor(sa, o); sc += __shfl_xor(sc, o); }
  if (i == 0) {
    float sv = sa * scale[bb];
    sv = sv / (1.0f + __expf(-sv));      // silu
    g[bb * 4 * DIM + r] = sv * (sc * scale[bb]);
  }
}

// ------ FFN w2 + residual, single pass (K=4096): one block per row ------
__global__ void ffn2_k(const float* __restrict__ g, const float* __restrict__ w2,
                       const float* __restrict__ resid, float* __restrict__ out) {
  __shared__ float lds[256 * 9];
  int r = blockIdx.x;                    // 0..1023
  int tid = threadIdx.x;
  const float* W = w2 + (size_t)r * 4 * DIM;
  float acc[8] = {};
#pragma unroll
  for (int j4 = 0; j4 < 4; ++j4) {
    int j = j4 * 1024 + tid * 4;
    float4 w4 = *(const float4*)(W + j);
#pragma unroll
    for (int bb = 0; bb < 8; ++bb) {
      float4 g4 = *(const float4*)(g + bb * 4 * DIM + j);
      acc[bb] += w4.x * g4.x + w4.y * g4.y + w4.z * g4.z + w4.w * g4.w;
    }
  }
  int bb; float s = block_reduce8(acc, lds, &bb);
  if ((tid & 31) == 0) out[bb * DIM + r] = s + resid[bb * DIM + r];
}

extern "C" void kernel_launch(void* const* d_in, const int* in_sizes, int n_in,
                              void* d_out, int out_size, void* d_ws, size_t ws_size,
                              hipStream_t stream) {
  const float* x0    = (const float*)d_in[0];
  const float* kheap = (const float*)d_in[1];
  const float* vheap = (const float*)d_in[2];
  const int*   bt    = (const int*)d_in[3];
  // d_in[4] = slot_mapping (int64) — unused; derived from context_lens instead.
  const int*   ctx   = (const int*)d_in[5];
  const float* wq    = (const float*)d_in[6];
  const float* wk    = (const float*)d_in[7];
  const float* wv    = (const float*)d_in[8];
  const float* wo    = (const float*)d_in[9];
  const float* w1    = (const float*)d_in[10];
  const float* w2    = (const float*)d_in[11];
  const float* w3    = (const float*)d_in[12];
  const float* norm1 = (const float*)d_in[13];
  const float* norm2 = (const float*)d_in[14];
  const float* normf = (const float*)d_in[15];

  float* ws = (float*)d_ws;
  float* q    = ws;                 // 8192
  float* k    = ws + 8192;          // 8192
  float* v    = ws + 16384;         // 8192
  float* g    = ws + 24576;         // 32768
  float* xa   = ws + 57344;         // 8192
  float* xf   = ws + 65536;         // 8192
  float* ab   = ws + 73728;         // 8192
  float* pm   = ws + 81920;         // 64*256 = 16384
  float* ps   = ws + 98304;         // 16384
  float* pacc = ws + 114688;        // 64*256*128 = 2097152 floats (8 MB)

  const size_t WD = (size_t)DIM * DIM;       // 1 MiB floats
  const size_t WF = (size_t)4 * DIM * DIM;   // 4 MiB floats

  for (int l = 0; l < LL; ++l) {
    const float* xin = (l == 0) ? x0 : xf;
    qkv_k<<<3072, 256, 0, stream>>>(xin, norm1 + l * DIM,
                                    wq + l * WD, wk + l * WD, wv + l * WD, q, k, v);
    attn_partial_k<<<dim3(NSPLIT, BB * NH), 256, 0, stream>>>(
        q, k, v, kheap, vheap, bt + l * BB * NB, ctx, pm, ps, pacc);
    attn_reduce_k<<<BB * NH, 256, 0, stream>>>(pm, ps, pacc, ab);
    proj_res_k<<<1024, 256, 0, stream>>>(ab, wo + l * WD, xin, xa);
    ffn13_k<<<4096, 256, 0, stream>>>(xa, norm2 + l * DIM, w1 + l * WF, w3 + l * WF, g);
    ffn2_k<<<1024, 256, 0, stream>>>(g, w2 + l * WF, xa, xf);
  }
  rmsnorm_k<<<BB, 256, 0, stream>>>(xf, normf, (float*)d_out);
}

// Round 10
// 134.111 us; speedup vs baseline: 17.5223x; 1.1101x over previous
//
#include <hip/hip_runtime.h>

#define BB    8
#define LL    2
#define DIM   1024
#define NH    8
#define HD    128
#define BS    16
#define NB    129
#define NSPLIT 32
#define SCALE 0.08838834764831845f   // 1/sqrt(128)
#define EPS   1e-5f

// ---- online-softmax single-token update ----
#define OS_UPDATE(mm, sss, AA, sc, v4) {          \
    float mnew = fmaxf(mm, sc);                   \
    float fo = __expf(mm - mnew);                 \
    float pr = __expf(sc - mnew);                 \
    sss = sss * fo + pr;                          \
    AA.x = AA.x * fo + pr * v4.x;                 \
    AA.y = AA.y * fo + pr * v4.y;                 \
    AA.z = AA.z * fo + pr * v4.z;                 \
    AA.w = AA.w * fo + pr * v4.w;                 \
    mm = mnew; }

// -------------------- final RMSNorm: one block per batch row --------------------
__global__ void rmsnorm_k(const float* __restrict__ x, const float* __restrict__ w,
                          float* __restrict__ out) {
  int b = blockIdx.x;
  float4 v = ((const float4*)(x + (size_t)b * DIM))[threadIdx.x];
  float s = v.x * v.x + v.y * v.y + v.z * v.z + v.w * v.w;
#pragma unroll
  for (int o = 32; o; o >>= 1) s += __shfl_xor(s, o);
  __shared__ float wsum[4];
  int wid = threadIdx.x >> 6;
  if ((threadIdx.x & 63) == 0) wsum[wid] = s;
  __syncthreads();
  float tot = wsum[0] + wsum[1] + wsum[2] + wsum[3];
  float r = rsqrtf(tot * (1.0f / DIM) + EPS);
  float4 wv = ((const float4*)w)[threadIdx.x];
  float4 o;
  o.x = v.x * r * wv.x; o.y = v.y * r * wv.y;
  o.z = v.z * r * wv.z; o.w = v.w * r * wv.w;
  ((float4*)(out + (size_t)b * DIM))[threadIdx.x] = o;
}

// ---- in-block rms scales: from 8 per-thread partials -> scale[8] in LDS ----
__device__ __forceinline__ void block_rms_scales(const float ss[8], float* lds,
                                                 float* scale) {
  int tid = threadIdx.x;
#pragma unroll
  for (int b = 0; b < 8; ++b) lds[tid * 9 + b] = ss[b];
  __syncthreads();
  int bb = tid >> 5, i = tid & 31;
  float s = 0.0f;
#pragma unroll
  for (int j = 0; j < 8; ++j) s += lds[(i + 32 * j) * 9 + bb];
#pragma unroll
  for (int o = 16; o; o >>= 1) s += __shfl_xor(s, o);
  if (i == 0) scale[bb] = rsqrtf(s * (1.0f / DIM) + EPS);
  __syncthreads();
}

// ---- LDS-transpose block reduce of 8 accumulators (safe back-to-back) ----
__device__ __forceinline__ float block_reduce8(const float acc[8], float* lds,
                                               int* bb_out) {
  int tid = threadIdx.x;
#pragma unroll
  for (int b = 0; b < 8; ++b) lds[tid * 9 + b] = acc[b];
  __syncthreads();
  int bb = tid >> 5, i = tid & 31;
  float s = 0.0f;
#pragma unroll
  for (int j = 0; j < 8; ++j) s += lds[(i + 32 * j) * 9 + bb];
#pragma unroll
  for (int o = 16; o; o >>= 1) s += __shfl_xor(s, o);
  __syncthreads();
  *bb_out = bb;
  return s;
}

// ------ QKV GEMV + fused RMSNorm: one block per TWO output rows (1536 blocks) ------
__global__ void qkv_k(const float* __restrict__ x, const float* __restrict__ nw,
                      const float* __restrict__ wq, const float* __restrict__ wk,
                      const float* __restrict__ wv,
                      float* __restrict__ q, float* __restrict__ k, float* __restrict__ v) {
  __shared__ float lds[256 * 9];
  __shared__ float scale[8];
  int tid = threadIdx.x;
  float4 xr[8];
  float ss[8];
#pragma unroll
  for (int bb = 0; bb < 8; ++bb) {
    xr[bb] = *(const float4*)(x + bb * DIM + tid * 4);
    ss[bb] = xr[bb].x * xr[bb].x + xr[bb].y * xr[bb].y +
             xr[bb].z * xr[bb].z + xr[bb].w * xr[bb].w;
  }
  block_rms_scales(ss, lds, scale);
  float4 wn = *(const float4*)(nw + tid * 4);
#pragma unroll
  for (int bb = 0; bb < 8; ++bb) {
    xr[bb].x *= wn.x; xr[bb].y *= wn.y; xr[bb].z *= wn.z; xr[bb].w *= wn.w;
  }

  int row0 = blockIdx.x * 2;             // 0..3070
  int mat0 = row0 >> 10, r0 = row0 & 1023;
  int row1 = row0 + 1;
  int mat1 = row1 >> 10, r1 = row1 & 1023;
  const float* W0 = (mat0 == 0 ? wq : mat0 == 1 ? wk : wv) + (size_t)r0 * DIM;
  const float* W1 = (mat1 == 0 ? wq : mat1 == 1 ? wk : wv) + (size_t)r1 * DIM;
  float4 w0 = *(const float4*)(W0 + tid * 4);
  float4 w1 = *(const float4*)(W1 + tid * 4);
  float a0[8], a1[8];
#pragma unroll
  for (int bb = 0; bb < 8; ++bb) {
    a0[bb] = w0.x * xr[bb].x + w0.y * xr[bb].y + w0.z * xr[bb].z + w0.w * xr[bb].w;
    a1[bb] = w1.x * xr[bb].x + w1.y * xr[bb].y + w1.z * xr[bb].z + w1.w * xr[bb].w;
  }
  int bb;
  float s0 = block_reduce8(a0, lds, &bb);
  float s1 = block_reduce8(a1, lds, &bb);
  if ((tid & 31) == 0) {
    float* d0 = (mat0 == 0 ? q : mat0 == 1 ? k : v);
    float* d1 = (mat1 == 0 ? q : mat1 == 1 ? k : v);
    d0[bb * DIM + r0] = s0 * scale[bb];
    d1[bb * DIM + r1] = s1 * scale[bb];
  }
}

// ------ flash-decode partial, ILP-2: grid (NSPLIT, B*H), 8 half-wave groups ------
__global__ void attn_partial_k(const float* __restrict__ qb, const float* __restrict__ kb,
                               const float* __restrict__ vb,
                               const float* __restrict__ kheap, const float* __restrict__ vheap,
                               const int* __restrict__ bt, const int* __restrict__ ctx_lens,
                               float* __restrict__ pm, float* __restrict__ ps,
                               float* __restrict__ pacc) {
  int c  = blockIdx.x;
  int bh = blockIdx.y;
  int b = bh >> 3, hh = bh & 7;
  int tid = threadIdx.x;
  int grp = tid >> 5, lane = tid & 31;
  int ctx = ctx_lens[b];
  int CH = (ctx + NSPLIT - 1) / NSPLIT;
  int t0 = c * CH;
  int t1 = t0 + CH; if (t1 > ctx) t1 = ctx;
  bool hasNew = (t1 == ctx);             // this unit owns the new token (pos ctx-1)
  int tlim = hasNew ? ctx - 1 : t1;      // heap tokens are in [t0, tlim)
  const float4 q4 = *(const float4*)(qb + (size_t)b * DIM + hh * HD + lane * 4);
  const int* btb = bt + b * NB;

  float m0 = -1e30f, m1 = -1e30f, s0 = 0.0f, s1 = 0.0f;
  float4 A0 = make_float4(0.f, 0.f, 0.f, 0.f);
  float4 A1 = make_float4(0.f, 0.f, 0.f, 0.f);

  int t = t0 + grp;
  for (; t + 8 < tlim; t += 16) {
    int ta = t, tb2 = t + 8;
    size_t base0 = ((((size_t)btb[ta >> 4] * BS) + (ta & 15)) * NH + hh) * HD;
    size_t base1 = ((((size_t)btb[tb2 >> 4] * BS) + (tb2 & 15)) * NH + hh) * HD;
    float4 k0 = *(const float4*)(kheap + base0 + lane * 4);
    float4 k1 = *(const float4*)(kheap + base1 + lane * 4);
    float4 v0 = *(const float4*)(vheap + base0 + lane * 4);
    float4 v1 = *(const float4*)(vheap + base1 + lane * 4);
    float sc0 = q4.x * k0.x + q4.y * k0.y + q4.z * k0.z + q4.w * k0.w;
    float sc1 = q4.x * k1.x + q4.y * k1.y + q4.z * k1.z + q4.w * k1.w;
#pragma unroll
    for (int o = 16; o; o >>= 1) {
      sc0 += __shfl_xor(sc0, o);
      sc1 += __shfl_xor(sc1, o);
    }
    sc0 *= SCALE; sc1 *= SCALE;
    OS_UPDATE(m0, s0, A0, sc0, v0);
    OS_UPDATE(m1, s1, A1, sc1, v1);
  }
  for (; t < tlim; t += 8) {             // at most one leftover heap token
    size_t base0 = ((((size_t)btb[t >> 4] * BS) + (t & 15)) * NH + hh) * HD;
    float4 k0 = *(const float4*)(kheap + base0 + lane * 4);
    float4 v0 = *(const float4*)(vheap + base0 + lane * 4);
    float sc0 = q4.x * k0.x + q4.y * k0.y + q4.z * k0.z + q4.w * k0.w;
#pragma unroll
    for (int o = 16; o; o >>= 1) sc0 += __shfl_xor(sc0, o);
    sc0 *= SCALE;
    OS_UPDATE(m0, s0, A0, sc0, v0);
  }
  if (hasNew && ((ctx - 1 - t0) & 7) == grp) {   // new token from fresh k/v buffers
    float4 k0 = *(const float4*)(kb + (size_t)b * DIM + hh * HD + lane * 4);
    float4 v0 = *(const float4*)(vb + (size_t)b * DIM + hh * HD + lane * 4);
    float sc0 = q4.x * k0.x + q4.y * k0.y + q4.z * k0.z + q4.w * k0.w;
#pragma unroll
    for (int o = 16; o; o >>= 1) sc0 += __shfl_xor(sc0, o);
    sc0 *= SCALE;
    OS_UPDATE(m0, s0, A0, sc0, v0);
  }

  float M = fmaxf(m0, m1);
  float f0 = __expf(m0 - M), f1 = __expf(m1 - M);
  float ssum = s0 * f0 + s1 * f1;
  float4 acc;
  acc.x = A0.x * f0 + A1.x * f1;
  acc.y = A0.y * f0 + A1.y * f1;
  acc.z = A0.z * f0 + A1.z * f1;
  acc.w = A0.w * f0 + A1.w * f1;

  int pi = bh * 256 + c * 8 + grp;
  if (lane == 0) { pm[pi] = M; ps[pi] = ssum; }
  *(float4*)(pacc + (size_t)pi * HD + lane * 4) = acc;
}

// ------ flash-decode reduce: one block per (b,h), 256 threads, 256 partials ------
__global__ void attn_reduce_k(const float* __restrict__ pm, const float* __restrict__ ps,
                              const float* __restrict__ pacc, float* __restrict__ ab) {
  int bh = blockIdx.x;
  int tid = threadIdx.x;   // 0..255
  __shared__ float red[256];
  __shared__ float fb[256];
  float mi = pm[bh * 256 + tid];
  red[tid] = mi; __syncthreads();
#pragma unroll
  for (int o = 128; o; o >>= 1) {
    if (tid < o) red[tid] = fmaxf(red[tid], red[tid + o]);
    __syncthreads();
  }
  float M = red[0]; __syncthreads();
  float fi = __expf(mi - M);
  fb[tid] = fi;
  red[tid] = ps[bh * 256 + tid] * fi;
  __syncthreads();
#pragma unroll
  for (int o = 128; o; o >>= 1) {
    if (tid < o) red[tid] += red[tid + o];
    __syncthreads();
  }
  float inv = 1.0f / red[0];
  int d = tid & 127, hp = tid >> 7;
  float od = 0.0f;
  const float* pb2 = pacc + ((size_t)bh * 256 + hp * 128) * HD + d;
  for (int p = 0; p < 128; ++p) od += pb2[(size_t)p * HD] * fb[hp * 128 + p];
  __syncthreads();
  red[tid] = od; __syncthreads();
  if (tid < 128) ab[bh * HD + tid] = (red[tid] + red[tid + 128]) * inv;
}

// ------ o-proj GEMV + residual: one block per TWO rows (512 blocks) ------
__global__ void proj_res_k(const float* __restrict__ in, const float* __restrict__ W0,
                           const float* __restrict__ resid, float* __restrict__ out) {
  __shared__ float lds[256 * 9];
  int r0 = blockIdx.x * 2, r1 = r0 + 1;
  int tid = threadIdx.x;
  float4 w0 = *(const float4*)(W0 + (size_t)r0 * DIM + tid * 4);
  float4 w1 = *(const float4*)(W0 + (size_t)r1 * DIM + tid * 4);
  float a0[8], a1[8];
#pragma unroll
  for (int bb = 0; bb < 8; ++bb) {
    float4 h4 = *(const float4*)(in + bb * DIM + tid * 4);
    a0[bb] = w0.x * h4.x + w0.y * h4.y + w0.z * h4.z + w0.w * h4.w;
    a1[bb] = w1.x * h4.x + w1.y * h4.y + w1.z * h4.z + w1.w * h4.w;
  }
  int bb;
  float s0 = block_reduce8(a0, lds, &bb);
  float s1 = block_reduce8(a1, lds, &bb);
  if ((tid & 31) == 0) {
    out[bb * DIM + r0] = s0 + resid[bb * DIM + r0];
    out[bb * DIM + r1] = s1 + resid[bb * DIM + r1];
  }
}

// ------ FFN w1/w3 + SwiGLU + fused RMSNorm: one block per TWO rows (2048 blocks) ------
__global__ void ffn13_k(const float* __restrict__ xa, const float* __restrict__ nw,
                        const float* __restrict__ w1, const float* __restrict__ w3,
                        float* __restrict__ g) {
  __shared__ float ldsA[256 * 9];
  __shared__ float ldsC[256 * 9];
  __shared__ float scale[8];
  int tid = threadIdx.x;
  float4 xr[8];
  float ss[8];
#pragma unroll
  for (int bb = 0; bb < 8; ++bb) {
    xr[bb] = *(const float4*)(xa + bb * DIM + tid * 4);
    ss[bb] = xr[bb].x * xr[bb].x + xr[bb].y * xr[bb].y +
             xr[bb].z * xr[bb].z + xr[bb].w * xr[bb].w;
  }
  block_rms_scales(ss, ldsA, scale);
  float4 wn = *(const float4*)(nw + tid * 4);
#pragma unroll
  for (int bb = 0; bb < 8; ++bb) {
    xr[bb].x *= wn.x; xr[bb].y *= wn.y; xr[bb].z *= wn.z; xr[bb].w *= wn.w;
  }

  int r0 = blockIdx.x * 2;
#pragma unroll
  for (int rr = 0; rr < 2; ++rr) {
    int r = r0 + rr;
    float4 w14 = *(const float4*)(w1 + (size_t)r * DIM + tid * 4);
    float4 w34 = *(const float4*)(w3 + (size_t)r * DIM + tid * 4);
    float a[8], c[8];
#pragma unroll
    for (int bb = 0; bb < 8; ++bb) {
      a[bb] = w14.x * xr[bb].x + w14.y * xr[bb].y + w14.z * xr[bb].z + w14.w * xr[bb].w;
      c[bb] = w34.x * xr[bb].x + w34.y * xr[bb].y + w34.z * xr[bb].z + w34.w * xr[bb].w;
    }
#pragma unroll
    for (int b = 0; b < 8; ++b) { ldsA[tid * 9 + b] = a[b]; ldsC[tid * 9 + b] = c[b]; }
    __syncthreads();
    int bb = tid >> 5, i = tid & 31;
    float sa = 0.0f, sc = 0.0f;
#pragma unroll
    for (int j = 0; j < 8; ++j) {
      sa += ldsA[(i + 32 * j) * 9 + bb];
      sc += ldsC[(i + 32 * j) * 9 + bb];
    }
#pragma unroll
    for (int o = 16; o; o >>= 1) { sa += __shfl_xor(sa, o); sc += __shfl_xor(sc, o); }
    if (i == 0) {
      float sv = sa * scale[bb];
      sv = sv / (1.0f + __expf(-sv));      // silu
      g[bb * 4 * DIM + r] = sv * (sc * scale[bb]);
    }
    __syncthreads();
  }
}

// ------ FFN w2 + residual (K=4096): one block per TWO rows (512 blocks) ------
__global__ void ffn2_k(const float* __restrict__ g, const float* __restrict__ w2,
                       const float* __restrict__ resid, float* __restrict__ out) {
  __shared__ float lds[256 * 9];
  int r0 = blockIdx.x * 2, r1 = r0 + 1;
  int tid = threadIdx.x;
  const float* W0 = w2 + (size_t)r0 * 4 * DIM;
  const float* W1 = w2 + (size_t)r1 * 4 * DIM;
  float a0[8] = {}, a1[8] = {};
#pragma unroll
  for (int j4 = 0; j4 < 4; ++j4) {
    int j = j4 * 1024 + tid * 4;
    float4 w0 = *(const float4*)(W0 + j);
    float4 w1 = *(const float4*)(W1 + j);
#pragma unroll
    for (int bb = 0; bb < 8; ++bb) {
      float4 g4 = *(const float4*)(g + bb * 4 * DIM + j);
      a0[bb] += w0.x * g4.x + w0.y * g4.y + w0.z * g4.z + w0.w * g4.w;
      a1[bb] += w1.x * g4.x + w1.y * g4.y + w1.z * g4.z + w1.w * g4.w;
    }
  }
  int bb;
  float s0 = block_reduce8(a0, lds, &bb);
  float s1 = block_reduce8(a1, lds, &bb);
  if ((tid & 31) == 0) {
    out[bb * DIM + r0] = s0 + resid[bb * DIM + r0];
    out[bb * DIM + r1] = s1 + resid[bb * DIM + r1];
  }
}

extern "C" void kernel_launch(void* const* d_in, const int* in_sizes, int n_in,
                              void* d_out, int out_size, void* d_ws, size_t ws_size,
                              hipStream_t stream) {
  const float* x0    = (const float*)d_in[0];
  const float* kheap = (const float*)d_in[1];
  const float* vheap = (const float*)d_in[2];
  const int*   bt    = (const int*)d_in[3];
  // d_in[4] = slot_mapping (int64) — unused; derived from context_lens instead.
  const int*   ctx   = (const int*)d_in[5];
  const float* wq    = (const float*)d_in[6];
  const float* wk    = (const float*)d_in[7];
  const float* wv    = (const float*)d_in[8];
  const float* wo    = (const float*)d_in[9];
  const float* w1    = (const float*)d_in[10];
  const float* w2    = (const float*)d_in[11];
  const float* w3    = (const float*)d_in[12];
  const float* norm1 = (const float*)d_in[13];
  const float* norm2 = (const float*)d_in[14];
  const float* normf = (const float*)d_in[15];

  float* ws = (float*)d_ws;
  float* q    = ws;                 // 8192
  float* k    = ws + 8192;          // 8192
  float* v    = ws + 16384;         // 8192
  float* g    = ws + 24576;         // 32768
  float* xa   = ws + 57344;         // 8192
  float* xf   = ws + 65536;         // 8192
  float* ab   = ws + 73728;         // 8192
  float* pm   = ws + 81920;         // 64*256 = 16384
  float* ps   = ws + 98304;         // 16384
  float* pacc = ws + 114688;        // 64*256*128 = 2097152 floats (8 MB)

  const size_t WD = (size_t)DIM * DIM;       // 1 MiB floats
  const size_t WF = (size_t)4 * DIM * DIM;   // 4 MiB floats

  for (int l = 0; l < LL; ++l) {
    const float* xin = (l == 0) ? x0 : xf;
    qkv_k<<<1536, 256, 0, stream>>>(xin, norm1 + l * DIM,
                                    wq + l * WD, wk + l * WD, wv + l * WD, q, k, v);
    attn_partial_k<<<dim3(NSPLIT, BB * NH), 256, 0, stream>>>(
        q, k, v, kheap, vheap, bt + l * BB * NB, ctx, pm, ps, pacc);
    attn_reduce_k<<<BB * NH, 256, 0, stream>>>(pm, ps, pacc, ab);
    proj_res_k<<<512, 256, 0, stream>>>(ab, wo + l * WD, xin, xa);
    ffn13_k<<<2048, 256, 0, stream>>>(xa, norm2 + l * DIM, w1 + l * WF, w3 + l * WF, g);
    ffn2_k<<<512, 256, 0, stream>>>(g, w2 + l * WF, xa, xf);
  }
  rmsnorm_k<<<BB, 256, 0, stream>>>(xf, normf, (float*)d_out);
}